// Round 2
// baseline (38.899 us; speedup 1.0000x reference)
//
#include <hip/hip_runtime.h>
#include <hip/hip_bf16.h>
#include <math.h>

// Problem constants (from reference setup_inputs)
constexpr int B_  = 192;
constexpr int NY  = 48;
constexpr int NT  = 48;
constexpr int C_  = 6625;

// DPP move: returns src[ctrl-mapped lane] for valid/written lanes, `identity`
// for invalid lanes / rows masked off by RM. All ctrl args compile-time.
template<int CTRL, int RM>
__device__ __forceinline__ float dpp_movf(float identity, float x) {
    int r = __builtin_amdgcn_update_dpp(__builtin_bit_cast(int, identity),
                                        __builtin_bit_cast(int, x),
                                        CTRL, RM, 0xf, false);
    return __builtin_bit_cast(float, r);
}

// DPP ctrl encodings (gfx9/CDNA): ROW_SHR|n = 0x110|n, WAVE_SHR1 = 0x138,
// ROW_BCAST15 = 0x142, ROW_BCAST31 = 0x143.

__global__ __launch_bounds__(1024) void ep_forward_kernel(
    const float* __restrict__ pred,
    const float* __restrict__ R,
    const float* __restrict__ I,
    const int*   __restrict__ tgt,
    float* __restrict__ logs,
    int*   __restrict__ cnt,
    float* __restrict__ out)
{
    __shared__ float sP[NT][NY];
    __shared__ float sI[NT][NY];
    __shared__ int   sT[NT];
    __shared__ int   sLast;
    __shared__ float sRed[4];

    const int b   = blockIdx.x;
    const int tid = threadIdx.x;

    if (tid == 0) sLast = 0;
    if (tid < NT) sT[tid] = tgt[b * NT + tid];
    __syncthreads();

    // ---- Phase 1: gather 2*48*48 = 4608 scattered floats into LDS ----
    const float* predB = pred + (size_t)b * NY * C_;
    const float* IB    = I    + (size_t)b * NY * C_;
    #pragma unroll
    for (int k = 0; k < 5; ++k) {
        int e = tid + k * 1024;
        if (e < 2 * NT * NY) {
            int arr = (e >= NT * NY);
            int i   = arr ? e - NT * NY : e;
            int t   = i / NY;
            int j   = i - t * NY;
            size_t off = (size_t)j * C_ + (size_t)sT[t];
            float v = fmaxf((arr ? IB : predB)[off], 0.0f);
            if (arr) sI[t][j] = v; else sP[t][j] = v;
        }
    }
    __syncthreads();

    // ---- Phase 2: recurrence on wave 0, lanes 0..47 (all DPP, no DS ops) ----
    if (tid < NY) {
        const int j = tid;
        const float* Rb = R + ((size_t)b * NY + j) * 3;
        float R0 = Rb[0];
        float R1 = Rb[1];
        float R2 = Rb[2];
        float Imult  = (j == NY - 1) ? 1.0f : R1;
        float R2prev = dpp_movf<0x138, 0xf>(0.0f, R2);   // R2[j-1], lane0 masked below

        // row0[j] = prod_{k=1..j} ((tgt[0]==1) ? 1 : R2[k])  (multiplicative scan)
        float d0 = (sT[0] == 1) ? 1.0f : R2;
        float v  = (j == 0) ? 1.0f : d0;
        v *= dpp_movf<0x111, 0xf>(1.0f, v);
        v *= dpp_movf<0x112, 0xf>(1.0f, v);
        v *= dpp_movf<0x114, 0xf>(1.0f, v);
        v *= dpp_movf<0x118, 0xf>(1.0f, v);
        v *= dpp_movf<0x142, 0xa>(1.0f, v);
        v *= dpp_movf<0x143, 0xc>(1.0f, v);
        float row = v;

        float pg = sP[0][j];
        float ig = sI[0][j];
        for (int t = 0; t < NT - 1; ++t) {
            // prefetch next t's LDS values (independent of scan chain)
            float pgn = sP[t + 1][j];
            float ign = sI[t + 1][j];

            // a[j] = row[j]*pI[j] + row[j-1]*pC[j-1]
            float u  = row * (R0 * pg);
            float up = dpp_movf<0x138, 0xf>(0.0f, u);     // lane0 -> 0
            float c  = fmaf(row, Imult * ig, up);

            // x_j = a_j + x_{j-1}*d_{j-1}; lane j's scan map multiplier m = d[j-1]
            float m = (j == 0) ? 0.0f : ((sT[t + 1] == 1) ? 1.0f : R2prev);

            // inclusive scan of affine maps (LLVM atomic-optimizer DPP pattern)
            { float mp = dpp_movf<0x111, 0xf>(1.0f, m), cp = dpp_movf<0x111, 0xf>(0.0f, c); c = fmaf(m, cp, c); m *= mp; }
            { float mp = dpp_movf<0x112, 0xf>(1.0f, m), cp = dpp_movf<0x112, 0xf>(0.0f, c); c = fmaf(m, cp, c); m *= mp; }
            { float mp = dpp_movf<0x114, 0xf>(1.0f, m), cp = dpp_movf<0x114, 0xf>(0.0f, c); c = fmaf(m, cp, c); m *= mp; }
            { float mp = dpp_movf<0x118, 0xf>(1.0f, m), cp = dpp_movf<0x118, 0xf>(0.0f, c); c = fmaf(m, cp, c); m *= mp; }
            { float mp = dpp_movf<0x142, 0xa>(1.0f, m), cp = dpp_movf<0x142, 0xa>(0.0f, c); c = fmaf(m, cp, c); m *= mp; }
            { float mp = dpp_movf<0x143, 0xc>(1.0f, m), cp = dpp_movf<0x143, 0xc>(0.0f, c); c = fmaf(m, cp, c); m *= mp; }
            row = c;

            pg = pgn; ig = ign;
        }

        if (j == NY - 1) {
            logs[b] = logf(row);
            __threadfence();   // release our log before signaling
            int old = __hip_atomic_fetch_add(cnt, 1, __ATOMIC_ACQ_REL,
                                             __HIP_MEMORY_SCOPE_AGENT);
            if (old == B_ - 1) sLast = 1;
        }
    }
    __syncthreads();

    // ---- Last block: deterministic fixed-order reduction of 192 logs ----
    if (sLast) {
        float x = 0.0f;
        if (tid < B_)
            x = __hip_atomic_load(&logs[tid], __ATOMIC_RELAXED,
                                  __HIP_MEMORY_SCOPE_AGENT);
        #pragma unroll
        for (int s = 1; s < 64; s <<= 1) x += __shfl_xor(x, s);
        if ((tid & 63) == 0 && tid < B_) sRed[tid >> 6] = x;
        __syncthreads();
        if (tid == 0) out[0] = (sRed[0] + sRed[1] + sRed[2]) * (1.0f / (float)B_);
    }
}

extern "C" void kernel_launch(void* const* d_in, const int* in_sizes, int n_in,
                              void* d_out, int out_size, void* d_ws, size_t ws_size,
                              hipStream_t stream) {
    const float* pred = (const float*)d_in[0];
    const float* R    = (const float*)d_in[1];
    const float* I    = (const float*)d_in[2];
    const int*   tgt  = (const int*)d_in[3];
    float* out  = (float*)d_out;
    float* logs = (float*)d_ws;                      // 192 floats
    int*   cnt  = (int*)((char*)d_ws + 768);         // completion counter

    hipMemsetAsync(cnt, 0, sizeof(int), stream);     // graph-capturable memset node
    ep_forward_kernel<<<B_, 1024, 0, stream>>>(pred, R, I, tgt, logs, cnt, out);
}